// Round 2
// baseline (839.542 us; speedup 1.0000x reference)
//
#include <hip/hip_runtime.h>
#include <hip/hip_bf16.h>
#include <hip/hip_fp16.h>
#include <string.h>

typedef unsigned short u16;
typedef __attribute__((ext_vector_type(8))) short short8;
typedef __attribute__((ext_vector_type(4))) float floatx4;
typedef __attribute__((ext_vector_type(16))) float floatx16;

#define N_TOK 4096
#define D_DIM 256
#define H_HEAD 8

__device__ __forceinline__ u16 f2b(float f){
  __hip_bfloat16 h = __float2bfloat16(f);
  return *reinterpret_cast<u16*>(&h);
}
__device__ __forceinline__ float b2f(u16 u){
  union { unsigned u; float f; } c; c.u = ((unsigned)u) << 16; return c.f;
}
__device__ __forceinline__ float h2f(u16 u){
  __half h; *reinterpret_cast<u16*>(&h) = u; return __half2float(h);
}
__device__ __forceinline__ u16 f2h(float f){
  __half h = __float2half(f); return *reinterpret_cast<u16*>(&h);
}

__device__ __forceinline__ void glds16(const void* g, void* l){
  __builtin_amdgcn_global_load_lds(
      (const __attribute__((address_space(1))) unsigned int*)g,
      (__attribute__((address_space(3))) unsigned int*)l, 16, 0, 0);
}

// ---------------- fused prep: weight cvt + qkv bias concat ----------------
__global__ void fused_prep(const float* __restrict__ Wq, const float* __restrict__ Wk,
                           const float* __restrict__ Wv, const float* __restrict__ Wo,
                           const float* __restrict__ Wff,
                           const float* __restrict__ bq, const float* __restrict__ bk,
                           const float* __restrict__ bv,
                           u16* __restrict__ wqkv, u16* __restrict__ wo_b,
                           u16* __restrict__ wff_b, float* __restrict__ bqkv){
  int bid = blockIdx.x;
  if (bid == 1056){
    int t = threadIdx.x;
    for (int j = 0; j < 24; ++j){
      int idx = t + j*256;
      float v;
      if (idx < 2048) v = bq[idx];
      else if (idx < 4096) v = bk[idx - 2048];
      else v = bv[idx - 4096];
      bqkv[idx] = v;
    }
    return;
  }
  const float* src; u16* dst; int base;
  if      (bid < 256) { src = Wq;  dst = wqkv;            base = bid; }
  else if (bid < 512) { src = Wk;  dst = wqkv + 524288;   base = bid - 256; }
  else if (bid < 768) { src = Wv;  dst = wqkv + 1048576;  base = bid - 512; }
  else if (bid < 1024){ src = Wo;  dst = wo_b;            base = bid - 768; }
  else                { src = Wff; dst = wff_b;           base = bid - 1024; }
  int i = (base*256 + threadIdx.x)*8;
  float4 a = *(const float4*)(src + i);
  float4 b = *(const float4*)(src + i + 4);
  u16 u[8] = {f2b(a.x),f2b(a.y),f2b(a.z),f2b(a.w),f2b(b.x),f2b(b.y),f2b(b.z),f2b(b.w)};
  *(short8*)(dst + i) = *(short8*)u;
}

// ---------------- layernorm: fp32 in -> bf16 out ----------------
__global__ void ln_kernel(const float* __restrict__ x, const float* __restrict__ g,
                          const float* __restrict__ b, u16* __restrict__ out){
  const int row = blockIdx.x;
  const int t = threadIdx.x;
  float v = x[(size_t)row*D_DIM + t];
  float s = v, ss = v*v;
  #pragma unroll
  for (int off = 32; off > 0; off >>= 1){
    s  += __shfl_down(s,  off);
    ss += __shfl_down(ss, off);
  }
  __shared__ float ls[4], lss[4];
  const int w = t >> 6, lane = t & 63;
  if (lane == 0){ ls[w] = s; lss[w] = ss; }
  __syncthreads();
  if (t == 0){
    float S  = ls[0]+ls[1]+ls[2]+ls[3];
    float SS = lss[0]+lss[1]+lss[2]+lss[3];
    float mu = S * (1.0f/D_DIM);
    float var = SS * (1.0f/D_DIM) - mu*mu;
    ls[0] = mu; lss[0] = rsqrtf(var + 1e-5f);
  }
  __syncthreads();
  float mu = ls[0], rs = lss[0];
  out[(size_t)row*D_DIM + t] = f2b((v - mu)*rs*g[t] + b[t]);
}

// ---------------- biasW: (spatial+edge)*log2e (fp16), pre-swizzled to MFMA C-layout ----
// layout: [q32 (128)][t (64)][lane (64)][j (32)], j = nb*16 + reg
// value = bias[q32*32 + (lane&31)][t*64 + 32nb + (reg&3) + 8*(reg>>2) + 4*(lane>>5)]
__global__ void make_biasW(const float* __restrict__ sp, const float* __restrict__ ed,
                           const int* __restrict__ mask, u16* __restrict__ out){
  __shared__ u16 bh[32][64];
  const int tg = blockIdx.x, q32 = blockIdx.y;
  const int t = threadIdx.x;
  const float L2E = 1.4426950408889634f;
  {
    int ql = t>>3, kc = (t&7)*8;
    size_t off = (size_t)(q32*32 + ql)*N_TOK + tg*64 + kc;
    float4 s0 = *(const float4*)(sp + off);
    float4 s1 = *(const float4*)(sp + off + 4);
    float4 e0 = *(const float4*)(ed + off);
    float4 e1 = *(const float4*)(ed + off + 4);
    int mr = mask[q32*32 + ql];
    int4 m0 = *(const int4*)(mask + tg*64 + kc);
    int4 m1 = *(const int4*)(mask + tg*64 + kc + 4);
    bh[ql][kc+0] = f2h((mr*m0.x)==0 ? -60000.f : (s0.x+e0.x)*L2E);
    bh[ql][kc+1] = f2h((mr*m0.y)==0 ? -60000.f : (s0.y+e0.y)*L2E);
    bh[ql][kc+2] = f2h((mr*m0.z)==0 ? -60000.f : (s0.z+e0.z)*L2E);
    bh[ql][kc+3] = f2h((mr*m0.w)==0 ? -60000.f : (s0.w+e0.w)*L2E);
    bh[ql][kc+4] = f2h((mr*m1.x)==0 ? -60000.f : (s1.x+e1.x)*L2E);
    bh[ql][kc+5] = f2h((mr*m1.y)==0 ? -60000.f : (s1.y+e1.y)*L2E);
    bh[ql][kc+6] = f2h((mr*m1.z)==0 ? -60000.f : (s1.z+e1.z)*L2E);
    bh[ql][kc+7] = f2h((mr*m1.w)==0 ? -60000.f : (s1.w+e1.w)*L2E);
  }
  __syncthreads();
  int lane2 = t>>2, j0 = (t&3)*8;
  u16 tmp[8];
  #pragma unroll
  for (int jj = 0; jj < 8; ++jj){
    int j = j0 + jj;
    int nb = j>>4, reg = j&15;
    int kvl = nb*32 + (reg&3) + 8*(reg>>2) + 4*(lane2>>5);
    tmp[jj] = bh[lane2&31][kvl];
  }
  u16* dst = out + (((size_t)q32*64 + tg)*64 + lane2)*32 + j0;
  *(short8*)dst = *(short8*)tmp;
}

// ---------------- V transpose: [h][n][e] -> [h][e][n], bf16 ----------------
__global__ void transpose_v(const u16* __restrict__ v, u16* __restrict__ vt){
  __shared__ u16 t[64][72];
  const int h = blockIdx.z;
  const int n0 = blockIdx.x*64, e0 = blockIdx.y*64;
  const int tid = threadIdx.x;
  const int r = tid >> 2;
  const int c = (tid & 3)*16;
  const u16* src = v + ((size_t)h*N_TOK + n0 + r)*D_DIM + e0 + c;
  short8 a = *(const short8*)src;
  short8 b = *(const short8*)(src + 8);
  #pragma unroll
  for (int i = 0; i < 8; ++i){ t[r][c+i] = ((u16*)&a)[i]; t[r][c+8+i] = ((u16*)&b)[i]; }
  __syncthreads();
  u16 tmp[16];
  #pragma unroll
  for (int i = 0; i < 16; ++i) tmp[i] = t[c+i][r];
  u16* dst = vt + ((size_t)h*D_DIM + e0 + r)*N_TOK + n0 + c;
  *(short8*)dst       = *(short8*)tmp;
  *(short8*)(dst + 8) = *(short8*)(tmp + 8);
}

// ---------------- bf16 GEMM, C = A * B^T (+bias, +resid) ----------------
// MODE 0: QKV — out bf16, col<2048 (Q) scaled by (1/16)*log2e folded for softmax.
// MODE 1/2: out fp32 = acc + bias[col] + resid[row*256+col].
template<int BM, int BN, int MODE>
__launch_bounds__(256, 2)
__global__ void gemm_bt(const u16* __restrict__ A, const u16* __restrict__ B, int K,
                        const float* __restrict__ bias, const float* __restrict__ resid,
                        void* __restrict__ Cout){
  constexpr int BK = 32;
  constexpr int WM = BM/2, WN = BN/2, FM = WM/16, FN = WN/16;
  constexpr int CApW = BM/64;
  constexpr int CBpW = BN/64;
  __shared__ u16 As[BM*BK];
  __shared__ u16 Bs[BN*BK];
  const int tid = threadIdx.x, w = tid>>6, lane = tid&63;
  const int quad = lane>>4, c16 = lane&15;
  const int wr = w>>1, wc = w&1;
  const int rowT = blockIdx.y*BM, colT = blockIdx.x*BN;
  const int lr = lane>>2;
  const int spos = lane&3;

  floatx4 acc[FM][FN] = {};

  for (int k0 = 0; k0 < K; k0 += BK){
    #pragma unroll
    for (int i = 0; i < CApW; ++i){
      int ch = w*CApW + i;
      int row = ch*16 + lr;
      int gch = spos ^ ((row>>1)&3);
      const u16* g = A + (size_t)(rowT + row)*K + k0 + gch*8;
      glds16(g, As + ch*512);
    }
    #pragma unroll
    for (int i = 0; i < CBpW; ++i){
      int ch = w*CBpW + i;
      int row = ch*16 + lr;
      int gch = spos ^ ((row>>1)&3);
      const u16* g = B + (size_t)(colT + row)*K + k0 + gch*8;
      glds16(g, Bs + ch*512);
    }
    __syncthreads();
    short8 af[FM], bf[FN];
    #pragma unroll
    for (int i = 0; i < FM; ++i){
      int row = wr*WM + i*16 + c16;
      int slot = quad ^ ((row>>1)&3);
      af[i] = *(const short8*)&As[row*BK + slot*8];
    }
    #pragma unroll
    for (int j = 0; j < FN; ++j){
      int row = wc*WN + j*16 + c16;
      int slot = quad ^ ((row>>1)&3);
      bf[j] = *(const short8*)&Bs[row*BK + slot*8];
    }
    #pragma unroll
    for (int i = 0; i < FM; ++i)
      #pragma unroll
      for (int j = 0; j < FN; ++j)
        acc[i][j] = __builtin_amdgcn_mfma_f32_16x16x32_bf16(af[i], bf[j], acc[i][j], 0, 0, 0);
    __syncthreads();
  }

  if (MODE == 0){
    u16* o = (u16*)Cout;
    #pragma unroll
    for (int i = 0; i < FM; ++i)
      #pragma unroll
      for (int j = 0; j < FN; ++j){
        int col = colT + wc*WN + j*16 + c16;
        float bv = bias[col];
        float sc = (col < 2048) ? 0.09016994374947424f : 1.0f; // (1/16)*log2e on Q
        size_t obase = (size_t)(col>>8)*((size_t)N_TOK*D_DIM) + (col & 255);
        #pragma unroll
        for (int r = 0; r < 4; ++r){
          int row = rowT + wr*WM + i*16 + quad*4 + r;
          o[obase + (size_t)row*D_DIM] = f2b((acc[i][j][r] + bv)*sc);
        }
      }
  } else {
    float* o = (float*)Cout;
    #pragma unroll
    for (int i = 0; i < FM; ++i)
      #pragma unroll
      for (int j = 0; j < FN; ++j){
        int col = colT + wc*WN + j*16 + c16;
        float bv = bias[col];
        #pragma unroll
        for (int r = 0; r < 4; ++r){
          int row = rowT + wr*WM + i*16 + quad*4 + r;
          size_t idx = (size_t)row*D_DIM + col;
          o[idx] = acc[i][j][r] + bv + resid[idx];
        }
      }
  }
}

// ---------------- flash attention, fixed-max, S^T/O^T via 32x32x16 MFMA ----------------
// grid (32 qtiles, 8 heads, 2 kv-splits), block 256 (4 waves x 32 q-rows)
// Writes partial O^T bf16 [h][e][q] per split + lsum fp32 [split][h][q].
__launch_bounds__(256, 2)
__global__ void attn_kernel(const u16* __restrict__ Q, const u16* __restrict__ Kg,
                            const u16* __restrict__ Vt, const u16* __restrict__ biasW,
                            u16* __restrict__ otp0, u16* __restrict__ otp1,
                            float* __restrict__ lsum){
  extern __shared__ __align__(16) u16 lds[];
  u16* Ks = lds;          // [64 kv][256 e], chunk-swizzled  (32 KB)
  u16* Vs = lds + 16384;  // [256 e][64 kv], chunk-swizzled  (32 KB)
  const int bx = blockIdx.x, h = blockIdx.y, spl = blockIdx.z;
  const int tid = threadIdx.x, w = tid>>6, lane = tid&63;
  const int l31 = lane&31, hi = lane>>5;
  const int qbase = bx*128 + w*32;
  const size_t hoff = (size_t)h*N_TOK*D_DIM;
  u16* otp = spl ? otp1 : otp0;

  // Q fragments (B-operand): lane holds Q[q=l31][e=16ks+8hi+j]
  short8 qf[16];
  {
    const u16* qp = Q + hoff + (size_t)(qbase + l31)*D_DIM + hi*8;
    #pragma unroll
    for (int ks = 0; ks < 16; ++ks) qf[ks] = *(const short8*)(qp + ks*16);
  }

  floatx16 o[8] = {};          // O^T accumulator: col q = l31, rows e
  float l4[4] = {0.f,0.f,0.f,0.f};

  const u16* Kb0 = Kg + hoff;
  const u16* Vb0 = Vt + hoff;
  const u16* bWb = biasW + (((size_t)(bx*4 + w)*64 + spl*32)*64 + lane)*32;

  for (int t = 0; t < 32; ++t){
    const int kv0 = spl*2048 + t*64;
    // bias loads (independent of LDS) — issue early
    const u16* bW = bWb + (size_t)t*64*32;
    short8 bv0 = *(const short8*)(bW);
    short8 bv1 = *(const short8*)(bW + 8);
    short8 bv2 = *(const short8*)(bW + 16);
    short8 bv3 = *(const short8*)(bW + 24);

    // stage K tile [64][256] and V^T tile [256][64], chunk-swizzled
    const u16* Kb = Kb0 + (size_t)kv0*D_DIM;
    const u16* Vb = Vb0 + kv0;
    #pragma unroll
    for (int i = 0; i < 8; ++i){
      int ch = w*8 + i;
      {
        int row = ch*2 + (lane>>5);
        int gch = (lane&31) ^ (row&7);
        glds16(Kb + (size_t)row*D_DIM + gch*8, Ks + ch*512);
      }
      {
        int row = ch*8 + (lane>>3);
        int gch = (lane&7) ^ (row&7);
        glds16(Vb + (size_t)row*N_TOK + gch*8, Vs + ch*512);
      }
    }
    __syncthreads();

    // ---- S^T = K Q^T : C col = q = l31, rows = kv ----
    floatx16 s0 = {}, s1 = {};
    #pragma unroll
    for (int ks = 0; ks < 16; ++ks){
      int sl = (2*ks + hi) ^ (l31&7);
      short8 k0 = *(const short8*)&Ks[l31*256 + sl*8];
      short8 k1 = *(const short8*)&Ks[(32 + l31)*256 + sl*8];
      s0 = __builtin_amdgcn_mfma_f32_32x32x16_bf16(k0, qf[ks], s0, 0, 0, 0);
      s1 = __builtin_amdgcn_mfma_f32_32x32x16_bf16(k1, qf[ks], s1, 0, 0, 0);
    }

    // ---- softmax (fixed max M=16, folded: p = exp2(s + b*log2e - 16*log2e)) ----
    unsigned pk[2][4][2];
    {
      float p0[16], p1[16];
      #pragma unroll
      for (int reg = 0; reg < 16; ++reg){
        float b0 = h2f(((u16*)&bv0)[0]); // placeholder overwritten below (unrolled)
        (void)b0;
      }
      // nb = 0
      #pragma unroll
      for (int reg = 0; reg < 16; ++reg){
        u16 hb = (reg < 8) ? ((u16*)&bv0)[reg] : ((u16*)&bv1)[reg-8];
        float e = exp2f(s0[reg] + h2f(hb) - 23.083120654223414f);
        p0[reg] = e; l4[reg&3] += e;
      }
      // nb = 1
      #pragma unroll
      for (int reg = 0; reg < 16; ++reg){
        u16 hb = (reg < 8) ? ((u16*)&bv2)[reg] : ((u16*)&bv3)[reg-8];
        float e = exp2f(s1[reg] + h2f(hb) - 23.083120654223414f);
        p1[reg] = e; l4[reg&3] += e;
      }
      #pragma unroll
      for (int a = 0; a < 4; ++a){
        pk[0][a][0] = (unsigned)f2b(p0[4*a+0]) | ((unsigned)f2b(p0[4*a+1]) << 16);
        pk[0][a][1] = (unsigned)f2b(p0[4*a+2]) | ((unsigned)f2b(p0[4*a+3]) << 16);
        pk[1][a][0] = (unsigned)f2b(p1[4*a+0]) | ((unsigned)f2b(p1[4*a+1]) << 16);
        pk[1][a][1] = (unsigned)f2b(p1[4*a+2]) | ((unsigned)f2b(p1[4*a+3]) << 16);
      }
    }

    // ---- O^T += V^T P^T : build P^T B-frags in-register via shfl_xor(32) ----
    #pragma unroll
    for (int ks2 = 0; ks2 < 4; ++ks2){
      int nb = ks2>>1, pp = ks2&1;
      unsigned lo0 = pk[nb][2*pp][0],   lo1 = pk[nb][2*pp][1];
      unsigned hA0 = pk[nb][2*pp+1][0], hA1 = pk[nb][2*pp+1][1];
      unsigned g0 = hi ? lo0 : hA0;   // word the partner lane needs
      unsigned g1 = hi ? lo1 : hA1;
      unsigned r0 = (unsigned)__shfl_xor((int)g0, 32, 64);
      unsigned r1 = (unsigned)__shfl_xor((int)g1, 32, 64);
      unsigned sf0 = hi ? hA0 : lo0;  // own word
      unsigned sf1 = hi ? hA1 : lo1;
      int4 fw;
      fw.x = (int)(hi ? r0 : sf0);
      fw.y = (int)(hi ? r1 : sf1);
      fw.z = (int)(hi ? sf0 : r0);
      fw.w = (int)(hi ? sf1 : r1);
      short8 pf = *(short8*)&fw;
      #pragma unroll
      for (int eb = 0; eb < 8; ++eb){
        int row = eb*32 + l31;
        int sl = (2*ks2 + hi) ^ (row&7);
        short8 vf = *(const short8*)&Vs[row*64 + sl*8];
        o[eb] = __builtin_amdgcn_mfma_f32_32x32x16_bf16(vf, pf, o[eb], 0, 0, 0);
      }
    }
    __syncthreads();
  }

  // ---- epilogue: per-split partial O^T (bf16) + l ----
  float l = l4[0] + l4[1] + l4[2] + l4[3];
  l += __shfl_xor(l, 32, 64);
  if (hi == 0)
    lsum[((size_t)spl*H_HEAD + h)*N_TOK + qbase + l31] = l;
  u16* ob = otp + (size_t)h*D_DIM*N_TOK + (qbase + l31);
  #pragma unroll
  for (int eb = 0; eb < 8; ++eb)
    #pragma unroll
    for (int reg = 0; reg < 16; ++reg){
      int e = eb*32 + (reg&3) + 8*(reg>>2) + 4*hi;
      ob[(size_t)e*N_TOK] = f2b(o[eb][reg]);
    }
}

// ---------------- combine: sum splits, normalize, transpose to cat[q][h*256+e] ----------------
__global__ void combine_kernel(const u16* __restrict__ o0, const u16* __restrict__ o1,
                               const float* __restrict__ lsum, u16* __restrict__ cat){
  __shared__ float tile[64][65];
  const int qt = blockIdx.x, et = blockIdx.y, h = blockIdx.z;
  const int t = threadIdx.x;
  {
    int er = t>>2, qc = (t&3)*16;
    size_t base = ((size_t)h*D_DIM + et*64 + er)*N_TOK + qt*64 + qc;
    short8 a0 = *(const short8*)(o0 + base);
    short8 a1 = *(const short8*)(o0 + base + 8);
    short8 b0 = *(const short8*)(o1 + base);
    short8 b1 = *(const short8*)(o1 + base + 8);
    #pragma unroll
    for (int i = 0; i < 8; ++i){
      tile[er][qc+i]   = b2f(((u16*)&a0)[i]) + b2f(((u16*)&b0)[i]);
      tile[er][qc+8+i] = b2f(((u16*)&a1)[i]) + b2f(((u16*)&b1)[i]);
    }
  }
  __syncthreads();
  int qr = t>>2, ec = (t&3)*16;
  int q = qt*64 + qr;
  float l = lsum[(size_t)h*N_TOK + q] + lsum[((size_t)H_HEAD + h)*N_TOK + q];
  float inv = (l > 0.f) ? 1.0f/l : 0.f;
  u16 tmp[16];
  #pragma unroll
  for (int i = 0; i < 16; ++i) tmp[i] = f2b(tile[ec+i][qr]*inv);
  u16* cp = cat + (size_t)q*(H_HEAD*D_DIM) + h*D_DIM + et*64 + ec;
  *(short8*)cp     = *(short8*)tmp;
  *(short8*)(cp+8) = *(short8*)(tmp+8);
}

// ---------------- launch ----------------
extern "C" void kernel_launch(void* const* d_in, const int* in_sizes, int n_in,
                              void* d_out, int out_size, void* d_ws, size_t ws_size,
                              hipStream_t stream){
  const float* x    = (const float*)d_in[0];
  const int*   mask = (const int*)  d_in[1];
  const float* sp   = (const float*)d_in[2];
  const float* ed   = (const float*)d_in[3];
  const float* g1   = (const float*)d_in[4];
  const float* b1   = (const float*)d_in[5];
  const float* Wq   = (const float*)d_in[6];
  const float* bq   = (const float*)d_in[7];
  const float* Wk   = (const float*)d_in[8];
  const float* bk   = (const float*)d_in[9];
  const float* Wv   = (const float*)d_in[10];
  const float* bv   = (const float*)d_in[11];
  const float* Wo   = (const float*)d_in[12];
  const float* bo   = (const float*)d_in[13];
  const float* g2   = (const float*)d_in[14];
  const float* b2   = (const float*)d_in[15];
  const float* Wff  = (const float*)d_in[16];
  const float* bff  = (const float*)d_in[17];
  float* out = (float*)d_out;
  char* ws = (char*)d_ws;

  constexpr size_t MB = 1ull<<20;
  u16*   wqkv   = (u16*)  (ws + 0);                 // 3 MB
  u16*   wo_b   = (u16*)  (ws + 3*MB);              // 1 MB
  u16*   wff_b  = (u16*)  (ws + 4*MB);              // 128 KB
  float* bqkv   = (float*)(ws + 4*MB + 256*1024);   // 24 KB
  u16*   xln    = (u16*)  (ws + 4*MB + 512*1024);   // 2 MB
  float* lsum   = (float*)(ws + 6*MB + 512*1024);   // 256 KB
  u16*   qkv    = (u16*)  (ws + 7*MB);              // 48 MB: Q@7, K@23, V@39
  u16*   vt     = (u16*)  (ws + 55*MB);             // 16 MB
  u16*   biasW  = (u16*)  (ws + 71*MB);             // 32 MB
  u16*   otp1   = (u16*)  (ws + 103*MB);            // 16 MB (split 1)
  u16*   otp0   = (u16*)  (ws + 39*MB);             // 16 MB (overlays dead V after transpose)
  u16*   cat    = (u16*)  (ws + 7*MB);              // 16 MB (overlays dead Q after attn)
  float* xout   = (float*)(ws + 23*MB);             // 4 MB (overlays dead K)
  u16*   xln2   = (u16*)  (ws + 27*MB);             // 2 MB
  const size_t TS = (size_t)H_HEAD*N_TOK*D_DIM;     // per-tensor elems

  // weights -> bf16, qkv bias concat
  fused_prep<<<1057, 256, 0, stream>>>(Wq, Wk, Wv, Wo, Wff, bq, bk, bv,
                                       wqkv, wo_b, wff_b, bqkv);
  // LN1
  ln_kernel<<<N_TOK, 256, 0, stream>>>(x, g1, b1, xln);

  // QKV projection (Q pre-scaled by (1/16)*log2e in epilogue)
  gemm_bt<128,128,0><<<dim3(48, 32), 256, 0, stream>>>(xln, wqkv, 256, bqkv, nullptr, qkv);

  // V transpose -> vt[h][e][n]
  transpose_v<<<dim3(64, 4, 8), 256, 0, stream>>>(qkv + 2*TS, vt);

  // swizzled combined bias
  make_biasW<<<dim3(64, 128), 256, 0, stream>>>(sp, ed, mask, biasW);

  // flash attention (fixed-max), 64 KB dynamic LDS
  hipFuncSetAttribute((const void*)attn_kernel,
                      hipFuncAttributeMaxDynamicSharedMemorySize, 65536);
  attn_kernel<<<dim3(32, 8, 2), 256, 65536, stream>>>(qkv, qkv + TS, vt, biasW,
                                                      otp0, otp1, lsum);

  // combine splits -> cat[q][h*256+e] bf16
  combine_kernel<<<dim3(64, 4, 8), 256, 0, stream>>>(otp0, otp1, lsum, cat);

  // output projection + residual
  gemm_bt<64,64,1><<<dim3(4, 64), 256, 0, stream>>>(cat, wo_b, 2048, bo, x, xout);

  // LN2
  ln_kernel<<<N_TOK, 256, 0, stream>>>(xout, g2, b2, xln2);

  // FF + residual
  gemm_bt<64,64,2><<<dim3(4, 64), 256, 0, stream>>>(xln2, wff_b, 256, bff, xout, out);
}

// Round 3
// 428.414 us; speedup vs baseline: 1.9597x; 1.9597x over previous
//
#include <hip/hip_runtime.h>
#include <hip/hip_bf16.h>
#include <hip/hip_fp16.h>
#include <string.h>

typedef unsigned short u16;
typedef __attribute__((ext_vector_type(8))) short short8;
typedef __attribute__((ext_vector_type(4))) float floatx4;
typedef __attribute__((ext_vector_type(16))) float floatx16;

#define N_TOK 4096
#define D_DIM 256
#define H_HEAD 8

__device__ __forceinline__ u16 f2b(float f){
  __hip_bfloat16 h = __float2bfloat16(f);
  return *reinterpret_cast<u16*>(&h);
}
__device__ __forceinline__ float b2f(u16 u){
  union { unsigned u; float f; } c; c.u = ((unsigned)u) << 16; return c.f;
}
__device__ __forceinline__ float h2f(u16 u){
  __half h; *reinterpret_cast<u16*>(&h) = u; return __half2float(h);
}
__device__ __forceinline__ u16 f2h(float f){
  __half h = __float2half(f); return *reinterpret_cast<u16*>(&h);
}

__device__ __forceinline__ void glds16(const void* g, void* l){
  __builtin_amdgcn_global_load_lds(
      (const __attribute__((address_space(1))) unsigned int*)g,
      (__attribute__((address_space(3))) unsigned int*)l, 16, 0, 0);
}

// ---------------- fused prep: weight cvt + qkv bias concat ----------------
__global__ void fused_prep(const float* __restrict__ Wq, const float* __restrict__ Wk,
                           const float* __restrict__ Wv, const float* __restrict__ Wo,
                           const float* __restrict__ Wff,
                           const float* __restrict__ bq, const float* __restrict__ bk,
                           const float* __restrict__ bv,
                           u16* __restrict__ wqkv, u16* __restrict__ wo_b,
                           u16* __restrict__ wff_b, float* __restrict__ bqkv){
  int bid = blockIdx.x;
  if (bid == 1056){
    int t = threadIdx.x;
    for (int j = 0; j < 24; ++j){
      int idx = t + j*256;
      float v;
      if (idx < 2048) v = bq[idx];
      else if (idx < 4096) v = bk[idx - 2048];
      else v = bv[idx - 4096];
      bqkv[idx] = v;
    }
    return;
  }
  const float* src; u16* dst; int base;
  if      (bid < 256) { src = Wq;  dst = wqkv;            base = bid; }
  else if (bid < 512) { src = Wk;  dst = wqkv + 524288;   base = bid - 256; }
  else if (bid < 768) { src = Wv;  dst = wqkv + 1048576;  base = bid - 512; }
  else if (bid < 1024){ src = Wo;  dst = wo_b;            base = bid - 768; }
  else                { src = Wff; dst = wff_b;           base = bid - 1024; }
  int i = (base*256 + threadIdx.x)*8;
  float4 a = *(const float4*)(src + i);
  float4 b = *(const float4*)(src + i + 4);
  u16 u[8] = {f2b(a.x),f2b(a.y),f2b(a.z),f2b(a.w),f2b(b.x),f2b(b.y),f2b(b.z),f2b(b.w)};
  *(short8*)(dst + i) = *(short8*)u;
}

// ---------------- layernorm: fp32 in -> bf16 out ----------------
__global__ void ln_kernel(const float* __restrict__ x, const float* __restrict__ g,
                          const float* __restrict__ b, u16* __restrict__ out){
  const int row = blockIdx.x;
  const int t = threadIdx.x;
  float v = x[(size_t)row*D_DIM + t];
  float s = v, ss = v*v;
  #pragma unroll
  for (int off = 32; off > 0; off >>= 1){
    s  += __shfl_down(s,  off);
    ss += __shfl_down(ss, off);
  }
  __shared__ float ls[4], lss[4];
  const int w = t >> 6, lane = t & 63;
  if (lane == 0){ ls[w] = s; lss[w] = ss; }
  __syncthreads();
  if (t == 0){
    float S  = ls[0]+ls[1]+ls[2]+ls[3];
    float SS = lss[0]+lss[1]+lss[2]+lss[3];
    float mu = S * (1.0f/D_DIM);
    float var = SS * (1.0f/D_DIM) - mu*mu;
    ls[0] = mu; lss[0] = rsqrtf(var + 1e-5f);
  }
  __syncthreads();
  float mu = ls[0], rs = lss[0];
  out[(size_t)row*D_DIM + t] = f2b((v - mu)*rs*g[t] + b[t]);
}

// ---------------- biasW: (spatial+edge)*log2e (fp16), pre-swizzled to MFMA C-layout ----
// layout: [q32 (128)][t (64)][lane (64)][j (32)], j = nb*16 + reg
// value = bias[q32*32 + (lane&31)][t*64 + 32nb + (reg&3) + 8*(reg>>2) + 4*(lane>>5)]
__global__ void make_biasW(const float* __restrict__ sp, const float* __restrict__ ed,
                           const int* __restrict__ mask, u16* __restrict__ out){
  __shared__ u16 bh[32][64];
  const int tg = blockIdx.x, q32 = blockIdx.y;
  const int t = threadIdx.x;
  const float L2E = 1.4426950408889634f;
  {
    int ql = t>>3, kc = (t&7)*8;
    size_t off = (size_t)(q32*32 + ql)*N_TOK + tg*64 + kc;
    float4 s0 = *(const float4*)(sp + off);
    float4 s1 = *(const float4*)(sp + off + 4);
    float4 e0 = *(const float4*)(ed + off);
    float4 e1 = *(const float4*)(ed + off + 4);
    int mr = mask[q32*32 + ql];
    int4 m0 = *(const int4*)(mask + tg*64 + kc);
    int4 m1 = *(const int4*)(mask + tg*64 + kc + 4);
    bh[ql][kc+0] = f2h((mr*m0.x)==0 ? -60000.f : (s0.x+e0.x)*L2E);
    bh[ql][kc+1] = f2h((mr*m0.y)==0 ? -60000.f : (s0.y+e0.y)*L2E);
    bh[ql][kc+2] = f2h((mr*m0.z)==0 ? -60000.f : (s0.z+e0.z)*L2E);
    bh[ql][kc+3] = f2h((mr*m0.w)==0 ? -60000.f : (s0.w+e0.w)*L2E);
    bh[ql][kc+4] = f2h((mr*m1.x)==0 ? -60000.f : (s1.x+e1.x)*L2E);
    bh[ql][kc+5] = f2h((mr*m1.y)==0 ? -60000.f : (s1.y+e1.y)*L2E);
    bh[ql][kc+6] = f2h((mr*m1.z)==0 ? -60000.f : (s1.z+e1.z)*L2E);
    bh[ql][kc+7] = f2h((mr*m1.w)==0 ? -60000.f : (s1.w+e1.w)*L2E);
  }
  __syncthreads();
  int lane2 = t>>2, j0 = (t&3)*8;
  u16 tmp[8];
  #pragma unroll
  for (int jj = 0; jj < 8; ++jj){
    int j = j0 + jj;
    int nb = j>>4, reg = j&15;
    int kvl = nb*32 + (reg&3) + 8*(reg>>2) + 4*(lane2>>5);
    tmp[jj] = bh[lane2&31][kvl];
  }
  u16* dst = out + (((size_t)q32*64 + tg)*64 + lane2)*32 + j0;
  *(short8*)dst = *(short8*)tmp;
}

// ---------------- V transpose: [h][n][e] -> [h][e][n], bf16 ----------------
__global__ void transpose_v(const u16* __restrict__ v, u16* __restrict__ vt){
  __shared__ u16 t[64][72];
  const int h = blockIdx.z;
  const int n0 = blockIdx.x*64, e0 = blockIdx.y*64;
  const int tid = threadIdx.x;
  const int r = tid >> 2;
  const int c = (tid & 3)*16;
  const u16* src = v + ((size_t)h*N_TOK + n0 + r)*D_DIM + e0 + c;
  short8 a = *(const short8*)src;
  short8 b = *(const short8*)(src + 8);
  #pragma unroll
  for (int i = 0; i < 8; ++i){ t[r][c+i] = ((u16*)&a)[i]; t[r][c+8+i] = ((u16*)&b)[i]; }
  __syncthreads();
  u16 tmp[16];
  #pragma unroll
  for (int i = 0; i < 16; ++i) tmp[i] = t[c+i][r];
  u16* dst = vt + ((size_t)h*D_DIM + e0 + r)*N_TOK + n0 + c;
  *(short8*)dst       = *(short8*)tmp;
  *(short8*)(dst + 8) = *(short8*)(tmp + 8);
}

// ---------------- bf16 GEMM, C = A * B^T (+bias, +resid) ----------------
template<int BM, int BN, int MODE>
__launch_bounds__(256, 2)
__global__ void gemm_bt(const u16* __restrict__ A, const u16* __restrict__ B, int K,
                        const float* __restrict__ bias, const float* __restrict__ resid,
                        void* __restrict__ Cout){
  constexpr int BK = 32;
  constexpr int WM = BM/2, WN = BN/2, FM = WM/16, FN = WN/16;
  constexpr int CApW = BM/64;
  constexpr int CBpW = BN/64;
  __shared__ u16 As[BM*BK];
  __shared__ u16 Bs[BN*BK];
  const int tid = threadIdx.x, w = tid>>6, lane = tid&63;
  const int quad = lane>>4, c16 = lane&15;
  const int wr = w>>1, wc = w&1;
  const int rowT = blockIdx.y*BM, colT = blockIdx.x*BN;
  const int lr = lane>>2;
  const int spos = lane&3;

  floatx4 acc[FM][FN] = {};

  for (int k0 = 0; k0 < K; k0 += BK){
    #pragma unroll
    for (int i = 0; i < CApW; ++i){
      int ch = w*CApW + i;
      int row = ch*16 + lr;
      int gch = spos ^ ((row>>1)&3);
      const u16* g = A + (size_t)(rowT + row)*K + k0 + gch*8;
      glds16(g, As + ch*512);
    }
    #pragma unroll
    for (int i = 0; i < CBpW; ++i){
      int ch = w*CBpW + i;
      int row = ch*16 + lr;
      int gch = spos ^ ((row>>1)&3);
      const u16* g = B + (size_t)(colT + row)*K + k0 + gch*8;
      glds16(g, Bs + ch*512);
    }
    __syncthreads();
    short8 af[FM], bf[FN];
    #pragma unroll
    for (int i = 0; i < FM; ++i){
      int row = wr*WM + i*16 + c16;
      int slot = quad ^ ((row>>1)&3);
      af[i] = *(const short8*)&As[row*BK + slot*8];
    }
    #pragma unroll
    for (int j = 0; j < FN; ++j){
      int row = wc*WN + j*16 + c16;
      int slot = quad ^ ((row>>1)&3);
      bf[j] = *(const short8*)&Bs[row*BK + slot*8];
    }
    #pragma unroll
    for (int i = 0; i < FM; ++i)
      #pragma unroll
      for (int j = 0; j < FN; ++j)
        acc[i][j] = __builtin_amdgcn_mfma_f32_16x16x32_bf16(af[i], bf[j], acc[i][j], 0, 0, 0);
    __syncthreads();
  }

  if (MODE == 0){
    u16* o = (u16*)Cout;
    #pragma unroll
    for (int i = 0; i < FM; ++i)
      #pragma unroll
      for (int j = 0; j < FN; ++j){
        int col = colT + wc*WN + j*16 + c16;
        float bv = bias[col];
        float sc = (col < 2048) ? 0.09016994374947424f : 1.0f; // (1/16)*log2e on Q
        size_t obase = (size_t)(col>>8)*((size_t)N_TOK*D_DIM) + (col & 255);
        #pragma unroll
        for (int r = 0; r < 4; ++r){
          int row = rowT + wr*WM + i*16 + quad*4 + r;
          o[obase + (size_t)row*D_DIM] = f2b((acc[i][j][r] + bv)*sc);
        }
      }
  } else {
    float* o = (float*)Cout;
    #pragma unroll
    for (int i = 0; i < FM; ++i)
      #pragma unroll
      for (int j = 0; j < FN; ++j){
        int col = colT + wc*WN + j*16 + c16;
        float bv = bias[col];
        #pragma unroll
        for (int r = 0; r < 4; ++r){
          int row = rowT + wr*WM + i*16 + quad*4 + r;
          size_t idx = (size_t)row*D_DIM + col;
          o[idx] = acc[i][j][r] + bv + resid[idx];
        }
      }
  }
}

// ---------------- flash attention, phase-split 8-wave blocks ----------------
// grid (32 qtiles, 8 heads, 2 kv-splits), block 512 (8 waves).
// S-phase: wave (qg=w>>1, kvh=w&1) computes 32kv x 32q quarter of S^T, softmax,
//          writes bf16 P^T to LDS [128 q][64 kv] (chunk-swizzled).
// PV-phase: wave (eh=w>>1, qh=w&1) computes O^T 64e x 64q from LDS V^T and P^T.
// K/V staging pipelined between the two barriers.
__launch_bounds__(512, 2)
__global__ void attn_kernel(const u16* __restrict__ Q, const u16* __restrict__ Kg,
                            const u16* __restrict__ Vt, const u16* __restrict__ biasW,
                            u16* __restrict__ otp0, u16* __restrict__ otp1,
                            float* __restrict__ lsum4){
  extern __shared__ __align__(16) u16 lds[];
  u16* Ks = lds;           // [64 kv][256 e] chunk-swizzled (32 KB)
  u16* Vs = lds + 16384;   // [256 e][64 kv] chunk-swizzled (32 KB)
  u16* Ps = lds + 32768;   // [128 q][64 kv] chunk-swizzled (16 KB)
  const int bx = blockIdx.x, h = blockIdx.y, spl = blockIdx.z;
  const int tid = threadIdx.x, w = tid>>6, lane = tid&63;
  const int hi = lane>>5, l31 = lane&31;
  const int qg = w>>1, kvh = w&1;   // S-phase role
  const int eh = w>>1, qh = w&1;    // PV-phase role
  const int qbase = bx*128;
  const size_t hoff = (size_t)h*N_TOK*D_DIM;
  u16* otp = spl ? otp1 : otp0;

  // Q B-frags (S-phase): lane holds Q[q = qbase+qg*32+l31][e = ks*16 + hi*8 + j]
  short8 qf[16];
  {
    const u16* qp = Q + hoff + (size_t)(qbase + qg*32 + l31)*D_DIM + hi*8;
    #pragma unroll
    for (int ks = 0; ks < 16; ++ks) qf[ks] = *(const short8*)(qp + ks*16);
  }

  floatx16 o00 = {}, o01 = {}, o10 = {}, o11 = {};
  float l_lane = 0.f;

  const u16* Kb0 = Kg + hoff + (size_t)spl*2048*D_DIM;
  const u16* Vb0 = Vt + hoff + spl*2048;
  const u16* bWb = biasW + ((((size_t)(bx*4 + qg))*64 + spl*32)*64 + lane)*32 + kvh*16;

  const int krow_s = (w*4)*2;          // staging helpers
  // prologue: stage tile 0 (K: 32 chunks of 2 rows; V: 32 chunks of 8 e-rows)
  {
    const u16* Kb = Kb0;
    const u16* Vb = Vb0;
    #pragma unroll
    for (int i = 0; i < 4; ++i){
      int ch = w*4 + i;
      int row = ch*2 + hi;
      int gch = l31 ^ (row&7);
      glds16(Kb + (size_t)row*D_DIM + gch*8, Ks + ch*512);
      int vrow = ch*8 + (lane>>3);
      int vgch = (lane&7) ^ (vrow&7);
      glds16(Vb + (size_t)vrow*N_TOK + vgch*8, Vs + ch*512);
    }
  }
  __syncthreads();

  for (int t = 0; t < 32; ++t){
    const int tn = (t + 1) & 31;   // wrap on last iter (harmless re-stage)

    // ---- S-phase: 32kv x 32q quarter ----
    const u16* bW = bWb + (size_t)t*64*32;
    short8 bv0 = *(const short8*)(bW);
    short8 bv1 = *(const short8*)(bW + 8);

    floatx16 sa = {}, sb = {};
    const int krow = kvh*32 + l31;
    #pragma unroll
    for (int ks = 0; ks < 16; ++ks){
      int slot = (2*ks + hi) ^ (l31&7);
      short8 ka = *(const short8*)&Ks[krow*256 + slot*8];
      if (ks & 1) sb = __builtin_amdgcn_mfma_f32_32x32x16_bf16(ka, qf[ks], sb, 0, 0, 0);
      else        sa = __builtin_amdgcn_mfma_f32_32x32x16_bf16(ka, qf[ks], sa, 0, 0, 0);
    }

    // softmax: p = exp2(s + bias*log2e - 16*log2e); bias pre-scaled, Q pre-scaled
    {
      const int q = qg*32 + l31;
      #pragma unroll
      for (int g = 0; g < 4; ++g){
        float p0, p1, p2, p3;
        {
          u16 b0 = (g < 2) ? ((u16*)&bv0)[4*g+0] : ((u16*)&bv1)[4*(g-2)+0];
          u16 b1 = (g < 2) ? ((u16*)&bv0)[4*g+1] : ((u16*)&bv1)[4*(g-2)+1];
          u16 b2 = (g < 2) ? ((u16*)&bv0)[4*g+2] : ((u16*)&bv1)[4*(g-2)+2];
          u16 b3 = (g < 2) ? ((u16*)&bv0)[4*g+3] : ((u16*)&bv1)[4*(g-2)+3];
          p0 = exp2f(sa[4*g+0] + sb[4*g+0] + h2f(b0) - 23.083120654223414f);
          p1 = exp2f(sa[4*g+1] + sb[4*g+1] + h2f(b1) - 23.083120654223414f);
          p2 = exp2f(sa[4*g+2] + sb[4*g+2] + h2f(b2) - 23.083120654223414f);
          p3 = exp2f(sa[4*g+3] + sb[4*g+3] + h2f(b3) - 23.083120654223414f);
        }
        l_lane += (p0 + p1) + (p2 + p3);
        uint2 pw;
        pw.x = (unsigned)f2b(p0) | ((unsigned)f2b(p1) << 16);
        pw.y = (unsigned)f2b(p2) | ((unsigned)f2b(p3) << 16);
        int slot = (kvh*4 + g) ^ (l31&7);
        *(uint2*)&Ps[q*64 + slot*8 + hi*4] = pw;
      }
    }
    __syncthreads();   // P ready; Ks reads done

    // stage K(t+1) — overlaps PV below
    {
      const u16* Kb = Kb0 + (size_t)tn*64*D_DIM;
      #pragma unroll
      for (int i = 0; i < 4; ++i){
        int ch = w*4 + i;
        int row = ch*2 + hi;
        int gch = l31 ^ (row&7);
        glds16(Kb + (size_t)row*D_DIM + gch*8, Ks + ch*512);
      }
    }

    // ---- PV-phase: O^T[e 64][q 64] ----
    #pragma unroll
    for (int ks2 = 0; ks2 < 4; ++ks2){
      int cA = ks2*2 + hi;
      int slA = cA ^ (l31&7);
      short8 vf0 = *(const short8*)&Vs[(eh*64 +      l31)*64 + slA*8];
      short8 vf1 = *(const short8*)&Vs[(eh*64 + 32 + l31)*64 + slA*8];
      short8 pf0 = *(const short8*)&Ps[(qh*64 +      l31)*64 + slA*8];
      short8 pf1 = *(const short8*)&Ps[(qh*64 + 32 + l31)*64 + slA*8];
      o00 = __builtin_amdgcn_mfma_f32_32x32x16_bf16(vf0, pf0, o00, 0, 0, 0);
      o01 = __builtin_amdgcn_mfma_f32_32x32x16_bf16(vf0, pf1, o01, 0, 0, 0);
      o10 = __builtin_amdgcn_mfma_f32_32x32x16_bf16(vf1, pf0, o10, 0, 0, 0);
      o11 = __builtin_amdgcn_mfma_f32_32x32x16_bf16(vf1, pf1, o11, 0, 0, 0);
    }
    __syncthreads();   // PV reads done; K(t+1) staged & drained

    // stage V(t+1) — drained at next loop's first barrier
    {
      const u16* Vb = Vb0 + tn*64;
      #pragma unroll
      for (int i = 0; i < 4; ++i){
        int ch = w*4 + i;
        int vrow = ch*8 + (lane>>3);
        int vgch = (lane&7) ^ (vrow&7);
        glds16(Vb + (size_t)vrow*N_TOK + vgch*8, Vs + ch*512);
      }
    }
  }

  // ---- epilogue ----
  l_lane += __shfl_xor(l_lane, 32, 64);
  if (hi == 0)
    lsum4[(((size_t)spl*2 + kvh)*H_HEAD + h)*N_TOK + qbase + qg*32 + l31] = l_lane;

  u16* ob = otp + (size_t)h*D_DIM*N_TOK;
  const int qA = qbase + qh*64 + l31;
  #pragma unroll
  for (int reg = 0; reg < 16; ++reg){
    int er = (reg&3) + 8*(reg>>2) + 4*hi;
    int e0 = eh*64 + er;
    ob[(size_t)e0*N_TOK + qA]            = f2b(o00[reg]);
    ob[(size_t)e0*N_TOK + qA + 32]       = f2b(o01[reg]);
    ob[(size_t)(e0+32)*N_TOK + qA]       = f2b(o10[reg]);
    ob[(size_t)(e0+32)*N_TOK + qA + 32]  = f2b(o11[reg]);
  }
}

// ---------------- combine: sum splits, normalize, transpose to cat[q][h*256+e] ----------------
__global__ void combine_kernel(const u16* __restrict__ o0, const u16* __restrict__ o1,
                               const float* __restrict__ lsum4, u16* __restrict__ cat){
  __shared__ float tile[64][65];
  const int qt = blockIdx.x, et = blockIdx.y, h = blockIdx.z;
  const int t = threadIdx.x;
  {
    int er = t>>2, qc = (t&3)*16;
    size_t base = ((size_t)h*D_DIM + et*64 + er)*N_TOK + qt*64 + qc;
    short8 a0 = *(const short8*)(o0 + base);
    short8 a1 = *(const short8*)(o0 + base + 8);
    short8 b0 = *(const short8*)(o1 + base);
    short8 b1 = *(const short8*)(o1 + base + 8);
    #pragma unroll
    for (int i = 0; i < 8; ++i){
      tile[er][qc+i]   = b2f(((u16*)&a0)[i]) + b2f(((u16*)&b0)[i]);
      tile[er][qc+8+i] = b2f(((u16*)&a1)[i]) + b2f(((u16*)&b1)[i]);
    }
  }
  __syncthreads();
  int qr = t>>2, ec = (t&3)*16;
  int q = qt*64 + qr;
  float l = 0.f;
  #pragma unroll
  for (int s2 = 0; s2 < 4; ++s2)
    l += lsum4[((size_t)s2*H_HEAD + h)*N_TOK + q];
  float inv = (l > 0.f) ? 1.0f/l : 0.f;
  u16 tmp[16];
  #pragma unroll
  for (int i = 0; i < 16; ++i) tmp[i] = f2b(tile[ec+i][qr]*inv);
  u16* cp = cat + (size_t)q*(H_HEAD*D_DIM) + h*D_DIM + et*64 + ec;
  *(short8*)cp     = *(short8*)tmp;
  *(short8*)(cp+8) = *(short8*)(tmp+8);
}

// ---------------- launch ----------------
extern "C" void kernel_launch(void* const* d_in, const int* in_sizes, int n_in,
                              void* d_out, int out_size, void* d_ws, size_t ws_size,
                              hipStream_t stream){
  const float* x    = (const float*)d_in[0];
  const int*   mask = (const int*)  d_in[1];
  const float* sp   = (const float*)d_in[2];
  const float* ed   = (const float*)d_in[3];
  const float* g1   = (const float*)d_in[4];
  const float* b1   = (const float*)d_in[5];
  const float* Wq   = (const float*)d_in[6];
  const float* bq   = (const float*)d_in[7];
  const float* Wk   = (const float*)d_in[8];
  const float* bk   = (const float*)d_in[9];
  const float* Wv   = (const float*)d_in[10];
  const float* bv   = (const float*)d_in[11];
  const float* Wo   = (const float*)d_in[12];
  const float* bo   = (const float*)d_in[13];
  const float* g2   = (const float*)d_in[14];
  const float* b2   = (const float*)d_in[15];
  const float* Wff  = (const float*)d_in[16];
  const float* bff  = (const float*)d_in[17];
  float* out = (float*)d_out;
  char* ws = (char*)d_ws;

  constexpr size_t MB = 1ull<<20;
  u16*   wqkv   = (u16*)  (ws + 0);                 // 3 MB
  u16*   wo_b   = (u16*)  (ws + 3*MB);              // 1 MB
  u16*   wff_b  = (u16*)  (ws + 4*MB);              // 128 KB
  float* bqkv   = (float*)(ws + 4*MB + 256*1024);   // 24 KB
  u16*   xln    = (u16*)  (ws + 4*MB + 512*1024);   // 2 MB
  float* lsum4  = (float*)(ws + 6*MB + 512*1024);   // 512 KB (4 partials)
  u16*   qkv    = (u16*)  (ws + 7*MB);              // 48 MB: Q@7, K@23, V@39
  u16*   vt     = (u16*)  (ws + 55*MB);             // 16 MB
  u16*   biasW  = (u16*)  (ws + 71*MB);             // 32 MB
  u16*   otp1   = (u16*)  (ws + 103*MB);            // 16 MB (split 1)
  u16*   otp0   = (u16*)  (ws + 39*MB);             // 16 MB (overlays dead V after transpose)
  u16*   cat    = (u16*)  (ws + 7*MB);              // 16 MB (overlays dead Q after attn)
  float* xout   = (float*)(ws + 23*MB);             // 4 MB (overlays dead K)
  u16*   xln2   = (u16*)  (ws + 27*MB);             // 2 MB
  const size_t TS = (size_t)H_HEAD*N_TOK*D_DIM;     // per-tensor elems

  // weights -> bf16, qkv bias concat
  fused_prep<<<1057, 256, 0, stream>>>(Wq, Wk, Wv, Wo, Wff, bq, bk, bv,
                                       wqkv, wo_b, wff_b, bqkv);
  // LN1
  ln_kernel<<<N_TOK, 256, 0, stream>>>(x, g1, b1, xln);

  // QKV projection (Q pre-scaled by (1/16)*log2e in epilogue)
  gemm_bt<128,128,0><<<dim3(48, 32), 256, 0, stream>>>(xln, wqkv, 256, bqkv, nullptr, qkv);

  // V transpose -> vt[h][e][n]
  transpose_v<<<dim3(64, 4, 8), 256, 0, stream>>>(qkv + 2*TS, vt);

  // swizzled combined bias
  make_biasW<<<dim3(64, 128), 256, 0, stream>>>(sp, ed, mask, biasW);

  // flash attention (phase-split, fixed-max), 80 KB dynamic LDS
  hipFuncSetAttribute((const void*)attn_kernel,
                      hipFuncAttributeMaxDynamicSharedMemorySize, 81920);
  attn_kernel<<<dim3(32, 8, 2), 512, 81920, stream>>>(qkv, qkv + TS, vt, biasW,
                                                      otp0, otp1, lsum4);

  // combine splits -> cat[q][h*256+e] bf16
  combine_kernel<<<dim3(64, 4, 8), 256, 0, stream>>>(otp0, otp1, lsum4, cat);

  // output projection + residual
  gemm_bt<64,64,1><<<dim3(4, 64), 256, 0, stream>>>(cat, wo_b, 2048, bo, x, xout);

  // LN2
  ln_kernel<<<N_TOK, 256, 0, stream>>>(xout, g2, b2, xln2);

  // FF + residual
  gemm_bt<64,64,2><<<dim3(4, 64), 256, 0, stream>>>(xln2, wff_b, 256, bff, xout, out);
}

// Round 4
// 422.612 us; speedup vs baseline: 1.9866x; 1.0137x over previous
//
#include <hip/hip_runtime.h>
#include <hip/hip_bf16.h>
#include <hip/hip_fp16.h>
#include <string.h>

typedef unsigned short u16;
typedef __attribute__((ext_vector_type(8))) short short8;
typedef __attribute__((ext_vector_type(4))) float floatx4;
typedef __attribute__((ext_vector_type(16))) float floatx16;

#define N_TOK 4096
#define D_DIM 256
#define H_HEAD 8

__device__ __forceinline__ u16 f2b(float f){
  __hip_bfloat16 h = __float2bfloat16(f);
  return *reinterpret_cast<u16*>(&h);
}
__device__ __forceinline__ float b2f(u16 u){
  union { unsigned u; float f; } c; c.u = ((unsigned)u) << 16; return c.f;
}
__device__ __forceinline__ float h2f(u16 u){
  __half h; *reinterpret_cast<u16*>(&h) = u; return __half2float(h);
}
__device__ __forceinline__ u16 f2h(float f){
  __half h = __float2half(f); return *reinterpret_cast<u16*>(&h);
}
__device__ __forceinline__ unsigned pk2bf(float a, float b){
  __hip_bfloat162 h = __float22bfloat162_rn(make_float2(a, b));
  return *reinterpret_cast<unsigned*>(&h);
}

__device__ __forceinline__ void glds16(const void* g, void* l){
  __builtin_amdgcn_global_load_lds(
      (const __attribute__((address_space(1))) unsigned int*)g,
      (__attribute__((address_space(3))) unsigned int*)l, 16, 0, 0);
}

// ---------------- fused prep: weight cvt + qkv bias concat ----------------
__global__ void fused_prep(const float* __restrict__ Wq, const float* __restrict__ Wk,
                           const float* __restrict__ Wv, const float* __restrict__ Wo,
                           const float* __restrict__ Wff,
                           const float* __restrict__ bq, const float* __restrict__ bk,
                           const float* __restrict__ bv,
                           u16* __restrict__ wqkv, u16* __restrict__ wo_b,
                           u16* __restrict__ wff_b, float* __restrict__ bqkv){
  int bid = blockIdx.x;
  if (bid == 1056){
    int t = threadIdx.x;
    for (int j = 0; j < 24; ++j){
      int idx = t + j*256;
      float v;
      if (idx < 2048) v = bq[idx];
      else if (idx < 4096) v = bk[idx - 2048];
      else v = bv[idx - 4096];
      bqkv[idx] = v;
    }
    return;
  }
  const float* src; u16* dst; int base;
  if      (bid < 256) { src = Wq;  dst = wqkv;            base = bid; }
  else if (bid < 512) { src = Wk;  dst = wqkv + 524288;   base = bid - 256; }
  else if (bid < 768) { src = Wv;  dst = wqkv + 1048576;  base = bid - 512; }
  else if (bid < 1024){ src = Wo;  dst = wo_b;            base = bid - 768; }
  else                { src = Wff; dst = wff_b;           base = bid - 1024; }
  int i = (base*256 + threadIdx.x)*8;
  float4 a = *(const float4*)(src + i);
  float4 b = *(const float4*)(src + i + 4);
  u16 u[8] = {f2b(a.x),f2b(a.y),f2b(a.z),f2b(a.w),f2b(b.x),f2b(b.y),f2b(b.z),f2b(b.w)};
  *(short8*)(dst + i) = *(short8*)u;
}

// ---------------- layernorm: fp32 in -> bf16 out ----------------
__global__ void ln_kernel(const float* __restrict__ x, const float* __restrict__ g,
                          const float* __restrict__ b, u16* __restrict__ out){
  const int row = blockIdx.x;
  const int t = threadIdx.x;
  float v = x[(size_t)row*D_DIM + t];
  float s = v, ss = v*v;
  #pragma unroll
  for (int off = 32; off > 0; off >>= 1){
    s  += __shfl_down(s,  off);
    ss += __shfl_down(ss, off);
  }
  __shared__ float ls[4], lss[4];
  const int w = t >> 6, lane = t & 63;
  if (lane == 0){ ls[w] = s; lss[w] = ss; }
  __syncthreads();
  if (t == 0){
    float S  = ls[0]+ls[1]+ls[2]+ls[3];
    float SS = lss[0]+lss[1]+lss[2]+lss[3];
    float mu = S * (1.0f/D_DIM);
    float var = SS * (1.0f/D_DIM) - mu*mu;
    ls[0] = mu; lss[0] = rsqrtf(var + 1e-5f);
  }
  __syncthreads();
  float mu = ls[0], rs = lss[0];
  out[(size_t)row*D_DIM + t] = f2b((v - mu)*rs*g[t] + b[t]);
}

// ---------------- ln_sum: x_out = p0+p1+bo+x ; LN2 -> bf16 ; also write x_out fp32 ----
__global__ void ln_sum(const float* __restrict__ p0, const float* __restrict__ p1,
                       const float* __restrict__ bo, const float* __restrict__ x,
                       const float* __restrict__ g, const float* __restrict__ b,
                       float* __restrict__ xout, u16* __restrict__ xln2){
  const int row = blockIdx.x;
  const int t = threadIdx.x;
  const size_t idx = (size_t)row*D_DIM + t;
  float v = p0[idx] + p1[idx] + bo[t] + x[idx];
  float s = v, ss = v*v;
  #pragma unroll
  for (int off = 32; off > 0; off >>= 1){
    s  += __shfl_down(s,  off);
    ss += __shfl_down(ss, off);
  }
  __shared__ float ls[4], lss[4];
  const int w = t >> 6, lane = t & 63;
  if (lane == 0){ ls[w] = s; lss[w] = ss; }
  __syncthreads();
  if (t == 0){
    float S  = ls[0]+ls[1]+ls[2]+ls[3];
    float SS = lss[0]+lss[1]+lss[2]+lss[3];
    float mu = S * (1.0f/D_DIM);
    float var = SS * (1.0f/D_DIM) - mu*mu;
    ls[0] = mu; lss[0] = rsqrtf(var + 1e-5f);
  }
  __syncthreads();
  float mu = ls[0], rs = lss[0];
  xout[idx] = v;
  xln2[idx] = f2b((v - mu)*rs*g[t] + b[t]);
}

// ---------------- biasW: (spatial+edge)*log2e fp16, masked=-inf, MFMA C-layout ----
__global__ void make_biasW(const float* __restrict__ sp, const float* __restrict__ ed,
                           const int* __restrict__ mask, u16* __restrict__ out){
  __shared__ u16 bh[32][64];
  const int tg = blockIdx.x, q32 = blockIdx.y;
  const int t = threadIdx.x;
  const float L2E = 1.4426950408889634f;
  const u16 NINF = 0xFC00;  // fp16 -inf
  {
    int ql = t>>3, kc = (t&7)*8;
    size_t off = (size_t)(q32*32 + ql)*N_TOK + tg*64 + kc;
    float4 s0 = *(const float4*)(sp + off);
    float4 s1 = *(const float4*)(sp + off + 4);
    float4 e0 = *(const float4*)(ed + off);
    float4 e1 = *(const float4*)(ed + off + 4);
    int mr = mask[q32*32 + ql];
    int4 m0 = *(const int4*)(mask + tg*64 + kc);
    int4 m1 = *(const int4*)(mask + tg*64 + kc + 4);
    bh[ql][kc+0] = (mr*m0.x)==0 ? NINF : f2h((s0.x+e0.x)*L2E);
    bh[ql][kc+1] = (mr*m0.y)==0 ? NINF : f2h((s0.y+e0.y)*L2E);
    bh[ql][kc+2] = (mr*m0.z)==0 ? NINF : f2h((s0.z+e0.z)*L2E);
    bh[ql][kc+3] = (mr*m0.w)==0 ? NINF : f2h((s0.w+e0.w)*L2E);
    bh[ql][kc+4] = (mr*m1.x)==0 ? NINF : f2h((s1.x+e1.x)*L2E);
    bh[ql][kc+5] = (mr*m1.y)==0 ? NINF : f2h((s1.y+e1.y)*L2E);
    bh[ql][kc+6] = (mr*m1.z)==0 ? NINF : f2h((s1.z+e1.z)*L2E);
    bh[ql][kc+7] = (mr*m1.w)==0 ? NINF : f2h((s1.w+e1.w)*L2E);
  }
  __syncthreads();
  int lane2 = t>>2, j0 = (t&3)*8;
  u16 tmp[8];
  #pragma unroll
  for (int jj = 0; jj < 8; ++jj){
    int j = j0 + jj;
    int nb = j>>4, reg = j&15;
    int kvl = nb*32 + (reg&3) + 8*(reg>>2) + 4*(lane2>>5);
    tmp[jj] = bh[lane2&31][kvl];
  }
  u16* dst = out + (((size_t)q32*64 + tg)*64 + lane2)*32 + j0;
  *(short8*)dst = *(short8*)tmp;
}

// ---------------- V transpose: [h][n][e] -> [h][e][n], bf16 ----------------
__global__ void transpose_v(const u16* __restrict__ v, u16* __restrict__ vt){
  __shared__ u16 t[64][72];
  const int h = blockIdx.z;
  const int n0 = blockIdx.x*64, e0 = blockIdx.y*64;
  const int tid = threadIdx.x;
  const int r = tid >> 2;
  const int c = (tid & 3)*16;
  const u16* src = v + ((size_t)h*N_TOK + n0 + r)*D_DIM + e0 + c;
  short8 a = *(const short8*)src;
  short8 b = *(const short8*)(src + 8);
  #pragma unroll
  for (int i = 0; i < 8; ++i){ t[r][c+i] = ((u16*)&a)[i]; t[r][c+8+i] = ((u16*)&b)[i]; }
  __syncthreads();
  u16 tmp[16];
  #pragma unroll
  for (int i = 0; i < 16; ++i) tmp[i] = t[c+i][r];
  u16* dst = vt + ((size_t)h*D_DIM + e0 + r)*N_TOK + n0 + c;
  *(short8*)dst       = *(short8*)tmp;
  *(short8*)(dst + 8) = *(short8*)(tmp + 8);
}

// ---------------- bf16 GEMM, C = A * B^T (+bias, +resid), lda/ldb pitches ----
// MODE 0: QKV — out bf16, col<2048 scaled by (1/16)*log2e.
// MODE 2: out fp32 = acc + bias[col] + resid[idx].
// MODE 3: split-K partial, out fp32 raw at Cout + z*N*D, k-offset z*K.
template<int BM, int BN, int MODE>
__launch_bounds__(256, 2)
__global__ void gemm_bt(const u16* __restrict__ A, const u16* __restrict__ B, int K,
                        int lda, int ldb,
                        const float* __restrict__ bias, const float* __restrict__ resid,
                        void* __restrict__ Cout){
  constexpr int BK = 32;
  constexpr int WM = BM/2, WN = BN/2, FM = WM/16, FN = WN/16;
  constexpr int CApW = BM/64;
  constexpr int CBpW = BN/64;
  __shared__ u16 As[BM*BK];
  __shared__ u16 Bs[BN*BK];
  const int tid = threadIdx.x, w = tid>>6, lane = tid&63;
  const int quad = lane>>4, c16 = lane&15;
  const int wr = w>>1, wc = w&1;
  const int rowT = blockIdx.y*BM, colT = blockIdx.x*BN;
  const int lr = lane>>2;
  const int spos = lane&3;
  const int koff = (MODE == 3) ? (int)blockIdx.z*K : 0;

  floatx4 acc[FM][FN] = {};

  for (int k0 = 0; k0 < K; k0 += BK){
    #pragma unroll
    for (int i = 0; i < CApW; ++i){
      int ch = w*CApW + i;
      int row = ch*16 + lr;
      int gch = spos ^ ((row>>1)&3);
      const u16* g = A + (size_t)(rowT + row)*lda + koff + k0 + gch*8;
      glds16(g, As + ch*512);
    }
    #pragma unroll
    for (int i = 0; i < CBpW; ++i){
      int ch = w*CBpW + i;
      int row = ch*16 + lr;
      int gch = spos ^ ((row>>1)&3);
      const u16* g = B + (size_t)(colT + row)*ldb + koff + k0 + gch*8;
      glds16(g, Bs + ch*512);
    }
    __syncthreads();
    short8 af[FM], bf[FN];
    #pragma unroll
    for (int i = 0; i < FM; ++i){
      int row = wr*WM + i*16 + c16;
      int slot = quad ^ ((row>>1)&3);
      af[i] = *(const short8*)&As[row*BK + slot*8];
    }
    #pragma unroll
    for (int j = 0; j < FN; ++j){
      int row = wc*WN + j*16 + c16;
      int slot = quad ^ ((row>>1)&3);
      bf[j] = *(const short8*)&Bs[row*BK + slot*8];
    }
    #pragma unroll
    for (int i = 0; i < FM; ++i)
      #pragma unroll
      for (int j = 0; j < FN; ++j)
        acc[i][j] = __builtin_amdgcn_mfma_f32_16x16x32_bf16(af[i], bf[j], acc[i][j], 0, 0, 0);
    __syncthreads();
  }

  if (MODE == 0){
    u16* o = (u16*)Cout;
    #pragma unroll
    for (int i = 0; i < FM; ++i)
      #pragma unroll
      for (int j = 0; j < FN; ++j){
        int col = colT + wc*WN + j*16 + c16;
        float bv = bias[col];
        float sc = (col < 2048) ? 0.09016994374947424f : 1.0f;
        size_t obase = (size_t)(col>>8)*((size_t)N_TOK*D_DIM) + (col & 255);
        #pragma unroll
        for (int r = 0; r < 4; ++r){
          int row = rowT + wr*WM + i*16 + quad*4 + r;
          o[obase + (size_t)row*D_DIM] = f2b((acc[i][j][r] + bv)*sc);
        }
      }
  } else if (MODE == 2){
    float* o = (float*)Cout;
    #pragma unroll
    for (int i = 0; i < FM; ++i)
      #pragma unroll
      for (int j = 0; j < FN; ++j){
        int col = colT + wc*WN + j*16 + c16;
        float bv = bias[col];
        #pragma unroll
        for (int r = 0; r < 4; ++r){
          int row = rowT + wr*WM + i*16 + quad*4 + r;
          size_t idx = (size_t)row*D_DIM + col;
          o[idx] = acc[i][j][r] + bv + resid[idx];
        }
      }
  } else {
    float* o = (float*)Cout + (size_t)blockIdx.z*((size_t)N_TOK*D_DIM);
    #pragma unroll
    for (int i = 0; i < FM; ++i)
      #pragma unroll
      for (int j = 0; j < FN; ++j){
        int col = colT + wc*WN + j*16 + c16;
        #pragma unroll
        for (int r = 0; r < 4; ++r){
          int row = rowT + wr*WM + i*16 + quad*4 + r;
          o[(size_t)row*D_DIM + col] = acc[i][j][r];
        }
      }
  }
}

// ---------------- flash attention, phase-split, O written in cat orientation ----
// grid (32 qtiles, 8 heads, 2 kv-splits), block 512 (8 waves).
// S-phase: wave (qg=w>>1, kvh=w&1): 32kv x 32q quarter of S^T -> softmax -> P^T LDS.
// PV-phase: wave (qh=w&1, ev=w>>1): O[q 64][e 64] = P[q][kv] * V^T[kv][e]
//           (A=P from Ps, B=V from Vs) -> writes cat_spl[q][h*256+e] bf16.
__launch_bounds__(512, 2)
__global__ void attn_kernel(const u16* __restrict__ Q, const u16* __restrict__ Kg,
                            const u16* __restrict__ Vt, const u16* __restrict__ biasW,
                            u16* __restrict__ cat0, u16* __restrict__ cat1,
                            float* __restrict__ lsum4){
  extern __shared__ __align__(16) u16 lds[];
  u16* Ks = lds;           // [64 kv][256 e] chunk-swizzled (32 KB)
  u16* Vs = lds + 16384;   // [256 e][64 kv] chunk-swizzled (32 KB)
  u16* Ps = lds + 32768;   // [128 q][64 kv] chunk-swizzled (16 KB)
  const int bx = blockIdx.x, h = blockIdx.y, spl = blockIdx.z;
  const int tid = threadIdx.x, w = tid>>6, lane = tid&63;
  const int hi = lane>>5, l31 = lane&31;
  const int qg = w>>1, kvh = w&1;   // S-phase role
  const int qh = w&1, ev = w>>1;    // PV-phase role
  const int qbase = bx*128;
  const size_t hoff = (size_t)h*N_TOK*D_DIM;
  u16* cs = spl ? cat1 : cat0;

  // Q B-frags (S-phase)
  short8 qf[16];
  {
    const u16* qp = Q + hoff + (size_t)(qbase + qg*32 + l31)*D_DIM + hi*8;
    #pragma unroll
    for (int ks = 0; ks < 16; ++ks) qf[ks] = *(const short8*)(qp + ks*16);
  }

  floatx16 o00 = {}, o01 = {}, o10 = {}, o11 = {};  // [qs][es]
  float l_lane = 0.f;

  const u16* Kb0 = Kg + hoff + (size_t)spl*2048*D_DIM;
  const u16* Vb0 = Vt + hoff + spl*2048;
  const u16* bWb = biasW + ((((size_t)(bx*4 + qg))*64 + spl*32)*64 + lane)*32 + kvh*16;

  // prologue: bias(0) + stage tile 0
  short8 bv0 = *(const short8*)(bWb);
  short8 bv1 = *(const short8*)(bWb + 8);
  {
    #pragma unroll
    for (int i = 0; i < 4; ++i){
      int ch = w*4 + i;
      int row = ch*2 + hi;
      int gch = l31 ^ (row&7);
      glds16(Kb0 + (size_t)row*D_DIM + gch*8, Ks + ch*512);
      int vrow = ch*8 + (lane>>3);
      int vgch = (lane&7) ^ (vrow&7);
      glds16(Vb0 + (size_t)vrow*N_TOK + vgch*8, Vs + ch*512);
    }
  }
  __syncthreads();

  for (int t = 0; t < 32; ++t){
    const int tn = (t + 1) & 31;

    // ---- S-phase ----
    floatx16 sa = {}, sb = {};
    const int krow = kvh*32 + l31;
    #pragma unroll
    for (int ks = 0; ks < 16; ++ks){
      int slot = (2*ks + hi) ^ (l31&7);
      short8 ka = *(const short8*)&Ks[krow*256 + slot*8];
      if (ks & 1) sb = __builtin_amdgcn_mfma_f32_32x32x16_bf16(ka, qf[ks], sb, 0, 0, 0);
      else        sa = __builtin_amdgcn_mfma_f32_32x32x16_bf16(ka, qf[ks], sa, 0, 0, 0);
    }

    // ---- softmax: p = exp2(s + bias)  (scale folded into Q, no max constant) ----
    {
      const int q = qg*32 + l31;
      #pragma unroll
      for (int g = 0; g < 4; ++g){
        u16 b0 = (g < 2) ? ((u16*)&bv0)[4*g+0] : ((u16*)&bv1)[4*(g-2)+0];
        u16 b1 = (g < 2) ? ((u16*)&bv0)[4*g+1] : ((u16*)&bv1)[4*(g-2)+1];
        u16 b2 = (g < 2) ? ((u16*)&bv0)[4*g+2] : ((u16*)&bv1)[4*(g-2)+2];
        u16 b3 = (g < 2) ? ((u16*)&bv0)[4*g+3] : ((u16*)&bv1)[4*(g-2)+3];
        float p0 = exp2f(sa[4*g+0] + sb[4*g+0] + h2f(b0));
        float p1 = exp2f(sa[4*g+1] + sb[4*g+1] + h2f(b1));
        float p2 = exp2f(sa[4*g+2] + sb[4*g+2] + h2f(b2));
        float p3 = exp2f(sa[4*g+3] + sb[4*g+3] + h2f(b3));
        l_lane += (p0 + p1) + (p2 + p3);
        uint2 pw;
        pw.x = pk2bf(p0, p1);
        pw.y = pk2bf(p2, p3);
        int slot = (kvh*4 + g) ^ (l31&7);
        *(uint2*)&Ps[q*64 + slot*8 + hi*4] = pw;
      }
    }
    __syncthreads();   // barrier 1: P visible, Ks reads done

    // stage K(t+1) + prefetch bias(t+1)
    {
      const u16* Kb = Kb0 + (size_t)tn*64*D_DIM;
      #pragma unroll
      for (int i = 0; i < 4; ++i){
        int ch = w*4 + i;
        int row = ch*2 + hi;
        int gch = l31 ^ (row&7);
        glds16(Kb + (size_t)row*D_DIM + gch*8, Ks + ch*512);
      }
      const u16* bW = bWb + (size_t)tn*64*32;
      bv0 = *(const short8*)(bW);
      bv1 = *(const short8*)(bW + 8);
    }

    // ---- PV-phase: O[q][e] ----
    #pragma unroll
    for (int ks2 = 0; ks2 < 4; ++ks2){
      int cA = ks2*2 + hi;
      int sl = cA ^ (l31&7);
      short8 pf0 = *(const short8*)&Ps[(qh*64 +      l31)*64 + sl*8];
      short8 pf1 = *(const short8*)&Ps[(qh*64 + 32 + l31)*64 + sl*8];
      short8 vf0 = *(const short8*)&Vs[(ev*64 +      l31)*64 + sl*8];
      short8 vf1 = *(const short8*)&Vs[(ev*64 + 32 + l31)*64 + sl*8];
      o00 = __builtin_amdgcn_mfma_f32_32x32x16_bf16(pf0, vf0, o00, 0, 0, 0);
      o01 = __builtin_amdgcn_mfma_f32_32x32x16_bf16(pf0, vf1, o01, 0, 0, 0);
      o10 = __builtin_amdgcn_mfma_f32_32x32x16_bf16(pf1, vf0, o10, 0, 0, 0);
      o11 = __builtin_amdgcn_mfma_f32_32x32x16_bf16(pf1, vf1, o11, 0, 0, 0);
    }
    __syncthreads();   // barrier 2: PV reads done, K(t+1) drained

    // stage V(t+1)
    {
      const u16* Vb = Vb0 + tn*64;
      #pragma unroll
      for (int i = 0; i < 4; ++i){
        int ch = w*4 + i;
        int vrow = ch*8 + (lane>>3);
        int vgch = (lane&7) ^ (vrow&7);
        glds16(Vb + (size_t)vrow*N_TOK + vgch*8, Vs + ch*512);
      }
    }
  }

  // ---- epilogue ----
  l_lane += __shfl_xor(l_lane, 32, 64);
  if (hi == 0)
    lsum4[(((size_t)spl*2 + kvh)*H_HEAD + h)*N_TOK + qbase + qg*32 + l31] = l_lane;

  #pragma unroll
  for (int reg = 0; reg < 16; ++reg){
    int qr = (reg&3) + 8*(reg>>2) + 4*hi;
    int q0 = qbase + qh*64 + qr;
    size_t c0 = (size_t)q0*(H_HEAD*D_DIM) + h*D_DIM + ev*64 + l31;
    size_t c1 = (size_t)(q0+32)*(H_HEAD*D_DIM) + h*D_DIM + ev*64 + l31;
    cs[c0]      = f2b(o00[reg]);
    cs[c0 + 32] = f2b(o01[reg]);
    cs[c1]      = f2b(o10[reg]);
    cs[c1 + 32] = f2b(o11[reg]);
  }
}

// ---------------- combine2: cat = (c0+c1) * inv_l[q,h], elementwise ----------------
__global__ void combine2(const u16* __restrict__ c0, const u16* __restrict__ c1,
                         const float* __restrict__ lsum4, u16* __restrict__ cat){
  const int q = blockIdx.x;
  const int t = threadIdx.x;
  const int col = t*8;
  const int h = t >> 5;
  float l = 0.f;
  #pragma unroll
  for (int s = 0; s < 4; ++s)
    l += lsum4[((size_t)s*H_HEAD + h)*N_TOK + q];
  float inv = (l > 0.f) ? 1.0f/l : 0.f;
  size_t base = (size_t)q*(H_HEAD*D_DIM) + col;
  short8 a = *(const short8*)(c0 + base);
  short8 b = *(const short8*)(c1 + base);
  u16 o[8];
  #pragma unroll
  for (int i = 0; i < 8; ++i)
    o[i] = f2b((b2f(((u16*)&a)[i]) + b2f(((u16*)&b)[i]))*inv);
  *(short8*)(cat + base) = *(short8*)o;
}

// ---------------- launch ----------------
extern "C" void kernel_launch(void* const* d_in, const int* in_sizes, int n_in,
                              void* d_out, int out_size, void* d_ws, size_t ws_size,
                              hipStream_t stream){
  const float* x    = (const float*)d_in[0];
  const int*   mask = (const int*)  d_in[1];
  const float* sp   = (const float*)d_in[2];
  const float* ed   = (const float*)d_in[3];
  const float* g1   = (const float*)d_in[4];
  const float* b1   = (const float*)d_in[5];
  const float* Wq   = (const float*)d_in[6];
  const float* bq   = (const float*)d_in[7];
  const float* Wk   = (const float*)d_in[8];
  const float* bk   = (const float*)d_in[9];
  const float* Wv   = (const float*)d_in[10];
  const float* bv   = (const float*)d_in[11];
  const float* Wo   = (const float*)d_in[12];
  const float* bo   = (const float*)d_in[13];
  const float* g2   = (const float*)d_in[14];
  const float* b2   = (const float*)d_in[15];
  const float* Wff  = (const float*)d_in[16];
  const float* bff  = (const float*)d_in[17];
  float* out = (float*)d_out;
  char* ws = (char*)d_ws;

  constexpr size_t MB = 1ull<<20;
  u16*   wqkv   = (u16*)  (ws + 0);                 // 3 MB
  u16*   wo_b   = (u16*)  (ws + 3*MB);              // 1 MB
  u16*   wff_b  = (u16*)  (ws + 4*MB);              // 128 KB
  float* bqkv   = (float*)(ws + 4*MB + 256*1024);   // 24 KB
  u16*   xln    = (u16*)  (ws + 4*MB + 512*1024);   // 2 MB
  float* lsum4  = (float*)(ws + 6*MB + 512*1024);   // 512 KB
  u16*   qkv    = (u16*)  (ws + 7*MB);              // 48 MB: Q@7, K@23, V@39
  u16*   vt     = (u16*)  (ws + 55*MB);             // 16 MB
  u16*   biasW  = (u16*)  (ws + 71*MB);             // 32 MB
  u16*   cat0   = (u16*)  (ws + 39*MB);             // 16 MB (overlays dead V)
  u16*   cat1   = (u16*)  (ws + 103*MB);            // 16 MB
  u16*   cat    = (u16*)  (ws + 7*MB);              // 16 MB (overlays dead Q)
  float* pK     = (float*)(ws + 23*MB);             // 8 MB  (overlays dead K)
  float* xout   = (float*)(ws + 31*MB);             // 4 MB
  u16*   xln2   = (u16*)  (ws + 35*MB);             // 2 MB
  const size_t TS = (size_t)H_HEAD*N_TOK*D_DIM;

  // weights -> bf16, qkv bias concat
  fused_prep<<<1057, 256, 0, stream>>>(Wq, Wk, Wv, Wo, Wff, bq, bk, bv,
                                       wqkv, wo_b, wff_b, bqkv);
  // LN1
  ln_kernel<<<N_TOK, 256, 0, stream>>>(x, g1, b1, xln);

  // QKV projection
  gemm_bt<128,128,0><<<dim3(48, 32), 256, 0, stream>>>(xln, wqkv, 256, 256, 256,
                                                       bqkv, nullptr, qkv);

  // V transpose
  transpose_v<<<dim3(64, 4, 8), 256, 0, stream>>>(qkv + 2*TS, vt);

  // swizzled combined bias (no constant offset, masked = -inf)
  make_biasW<<<dim3(64, 128), 256, 0, stream>>>(sp, ed, mask, biasW);

  // flash attention
  hipFuncSetAttribute((const void*)attn_kernel,
                      hipFuncAttributeMaxDynamicSharedMemorySize, 81920);
  attn_kernel<<<dim3(32, 8, 2), 512, 81920, stream>>>(qkv, qkv + TS, vt, biasW,
                                                      cat0, cat1, lsum4);

  // combine splits + normalize (elementwise)
  combine2<<<N_TOK, 256, 0, stream>>>(cat0, cat1, lsum4, cat);

  // output projection, split-K=2, raw fp32 partials
  gemm_bt<64,64,3><<<dim3(4, 64, 2), 256, 0, stream>>>(cat, wo_b, 1024, 2048, 2048,
                                                       nullptr, nullptr, pK);

  // sum partials + bo + x residual + LN2
  ln_sum<<<N_TOK, 256, 0, stream>>>(pK, pK + (size_t)N_TOK*D_DIM, bo, x, g2, b2,
                                    xout, xln2);

  // FF + residual
  gemm_bt<64,64,2><<<dim3(4, 64), 256, 0, stream>>>(xln2, wff_b, 256, 256, 256,
                                                    bff, xout, out);
}